// Round 6
// baseline (229.082 us; speedup 1.0000x reference)
//
#include <hip/hip_runtime.h>
#include <math.h>

#define Tt 250
#define TnN 243
#define Nn 256
#define EPS_ 1e-5f
#define LOG2E 1.44269504f

typedef unsigned short u16;
typedef __bf16 bf16x8 __attribute__((ext_vector_type(8)));
typedef float f32x4 __attribute__((ext_vector_type(4)));

__device__ __forceinline__ u16 f2bf(float f) {
    unsigned u = __builtin_bit_cast(unsigned, f);
    u += 0x7FFFu + ((u >> 16) & 1u);
    return (u16)(u >> 16);
}
__device__ __forceinline__ float bf2f(u16 s) {
    unsigned u = ((unsigned)s) << 16;
    return __builtin_bit_cast(float, u);
}
__device__ __forceinline__ float hw_exp2(float x) {
    return __builtin_amdgcn_exp2f(x);
}

__device__ __forceinline__ void async_load16(const void* g, void* l) {
    __builtin_amdgcn_global_load_lds(
        (const __attribute__((address_space(1))) unsigned int*)g,
        (__attribute__((address_space(3))) unsigned int*)l, 16, 0, 0);
}

// generalized padded-row DMA: LDS rows of 72 u16 (64 valid + 8 pad), global rows of rstride u16.
// nseg segments of 1024B; seg s covers linear chunks [s*64, s*64+64).
__device__ __forceinline__ void dma72g(const u16* gsrc, int rstride, u16* ldst, int nseg,
                                       int w, int lane, int nw) {
    for (int seg = w; seg < nseg; seg += nw) {
        int c9 = seg * 64 + lane;
        int row = c9 / 9, sub = c9 - row * 9;
        const u16* src = (sub < 8) ? &gsrc[row * rstride + sub * 8] : gsrc;
        async_load16(src, ldst + seg * 512);
    }
}

// serial c-chain over one transposed row pair, direction D compile-time.
template<int D>
__device__ __forceinline__ void chain_run(u16* Zr, u16* Fr, float kf, float bf_) {
    bf16x8 z8 = *(const bf16x8*)&Zr[D ? 240 : 0];
    bf16x8 f8 = *(const bf16x8*)&Fr[D ? 240 : 0];
    float c = 0.f;
    for (int grp = 0; grp < 31; ++grp) {
        int gb = D ? (30 - grp) * 8 : grp * 8;
        bf16x8 zn = z8, fn = f8;
        if (grp < 30) {
            int gbn = D ? (29 - grp) * 8 : (grp + 1) * 8;
            zn = *(const bf16x8*)&Zr[gbn];
            fn = *(const bf16x8*)&Fr[gbn];
        }
        bf16x8 co;
        #pragma unroll
        for (int k = 0; k < 8; ++k) {
            const int idx = D ? (7 - k) : k;
            int t = gb + idx;
            float uz = (float)z8[idx];
            float af = -LOG2E * ((float)f8[idx] + bf_);
            float xe = fmaf(kf, c, af);
            float fg = __builtin_amdgcn_rcpf(1.f + hw_exp2(xe));
            float cn = fmaf(fg, c - uz, uz);
            bool ok = (t < TnN);
            if (ok) c = cn;
            co[idx] = ok ? (__bf16)c : (__bf16)0.f;
        }
        *(bf16x8*)&Zr[gb] = co;
        z8 = zn; f8 = fn;
    }
}

// ---------------- combined prep: blocks 0..831 pack weights, 832..1087 stats ----------------
__global__ __launch_bounds__(256) void k_prep(const float* __restrict__ x,
                                              const float* __restrict__ W0,
                                              const float* __restrict__ Wr,
                                              const float* __restrict__ wct,
                                              float* __restrict__ stats,
                                              u16* __restrict__ W0k,
                                              u16* __restrict__ Wrt,
                                              u16* __restrict__ Wcto) {
    __shared__ float ls[4], ls2[4];
    const int bx = blockIdx.x, tid = threadIdx.x;
    if (bx < 832) {
        int idx = bx * 256 + tid;
        if (idx < 131072) {
            int k = idx >> 14, j = (idx >> 6) & 255, c = idx & 63;
            int d = j >> 7, ck = c * 8 + k;
            W0k[idx] = f2bf(W0[((size_t)d * 512 + ck) * 128 + (j & 127)]);
        } else if (idx < 180224) {
            int r = idx - 131072;
            int i = r & 63, j = (r >> 6) & 255, lidx = r >> 14;
            Wrt[r] = f2bf(Wr[(size_t)(lidx * 2 + (j >> 7)) * 8192 + i * 128 + (j & 127)]);
        } else {
            int r = idx - 180224;
            int o = r >> 9; int k = r & 511; int kk = k >> 6, ci = k & 63;
            Wcto[r] = f2bf(wct[(size_t)ci * 512 + o * 8 + kk]);
        }
    } else {
        const int sb = bx - 832;           // 0..255
        const int b = sb >> 7;             // 0,1
        const float4* xb = (const float4*)(x + (size_t)b * 64 * 128 * Tt);
        const int n4 = 64 * 128 * Tt / 4;  // 512000
        float s = 0.f, s2 = 0.f;
        for (int i = (sb & 127) * 256 + tid; i < n4; i += 128 * 256) {
            float4 vv = xb[i];
            s  += vv.x + vv.y + vv.z + vv.w;
            s2 += vv.x * vv.x + vv.y * vv.y + vv.z * vv.z + vv.w * vv.w;
        }
        for (int off = 32; off; off >>= 1) {
            s  += __shfl_down(s, off);
            s2 += __shfl_down(s2, off);
        }
        int lane = tid & 63, w = tid >> 6;
        if (lane == 0) { ls[w] = s; ls2[w] = s2; }
        __syncthreads();
        if (tid == 0) {
            float a = 0.f, a2 = 0.f;
            for (int i = 0; i < 4; i++) { a += ls[i]; a2 += ls2[i]; }
            atomicAdd(&stats[b * 2 + 0], a);
            atomicAdd(&stats[b * 2 + 1], a2);
        }
    }
}

// GEMM epilogue (16-wave): acc[16] -> ZT/FT (transposed [h][t]) and Rs/Xs ([t][h] planes)
__device__ __forceinline__ void epi16(f32x4 (&acc)[16], u16* ZT, u16* FT, u16* Rs, u16* Xs,
                                      int w, int ml, int q) {
    int t0 = w * 16 + q * 4;
    if (t0 >= TnN) return;
    bool vec = (t0 + 4 <= TnN);
    #pragma unroll
    for (int nt = 0; nt < 16; ++nt) {
        int d2 = nt >> 3, g2 = (nt >> 1) & 3, hh = (nt & 1) * 16 + ml;
        if (g2 < 2) {
            u16* P = (g2 ? FT : ZT) + (d2 * 32 + hh) * 248;
            if (vec) {
                uint2 pv;
                pv.x = (unsigned)f2bf(acc[nt][0]) | ((unsigned)f2bf(acc[nt][1]) << 16);
                pv.y = (unsigned)f2bf(acc[nt][2]) | ((unsigned)f2bf(acc[nt][3]) << 16);
                *(uint2*)&P[t0] = pv;
            } else {
                #pragma unroll
                for (int r = 0; r < 4; ++r) {
                    int t = t0 + r;
                    if (t < TnN) P[t] = f2bf(acc[nt][r]);
                }
            }
        } else {
            u16* P = (g2 == 2 ? Rs : Xs) + d2 * 7776 + hh;
            #pragma unroll
            for (int r = 0; r < 4; ++r) {
                int t = t0 + r;
                if (t < TnN) P[t * 32] = f2bf(acc[nt][r]);
            }
        }
    }
}

// ---------------- mega tail (1024 threads / 16 waves) ----------------
// LDS map (u16 offsets): Hs 0..19007 (264x72), ZT 19008 (64x248), FT 34880 (64x248),
//                        Rs 50752 (2x243x32), Xs 66304 (2x243x32). Total 81856 u16 = 163,712 B
// lay0: Hs holds normalized-x tile [256][72]; B dbuf at ZT0 / ZT0+18432; lt staging at 55872.
#define HS0 0
#define ZT0 19008
#define FT0 34880
#define RS0 50752
#define XS0 66304
#define LT0 55872
#define SH_U16 81856
__global__ __launch_bounds__(1024) void k_tail(const float* __restrict__ stats,
                                               const u16* __restrict__ W0k,
                                               const u16* __restrict__ Wrt,
                                               const u16* __restrict__ Wc,
                                               const float* __restrict__ v,
                                               const float* __restrict__ bbias,
                                               const float* __restrict__ bct,
                                               const float* __restrict__ gamma,
                                               const float* __restrict__ beta,
                                               const float* __restrict__ x,
                                               float* __restrict__ out) {
    __shared__ __align__(16) u16 sh[SH_U16];
    u16* Hs = sh + HS0;
    u16* ZT = sh + ZT0;
    u16* FT = sh + FT0;
    u16* Rs = sh + RS0;
    u16* Xs = sh + XS0;
    const int tid = threadIdx.x;
    const int n = blockIdx.x;
    const int lane = tid & 63, w = tid >> 6;          // w in 0..15
    const int ml = lane & 15, q = lane >> 4;
    const int b = n >> 7, f = n & 127;

    for (int lay = 0; lay < 4; ++lay) {
        if (lay == 0) {
            // ---- fused normalize + transpose: x[b,:,f,:] -> Hs[t][c] (bf16, rows 0..255)
            const float inv = 1.0f / (float)(64 * 128 * Tt);
            float mean = stats[b * 2 + 0] * inv;
            float var  = stats[b * 2 + 1] * inv - mean * mean;
            float rstd = rsqrtf(var + EPS_);
            u16* lt = sh + LT0;                        // [64 c][260 t] staging
            #pragma unroll
            for (int rr = 0; rr < 4; ++rr) {
                int c = w * 4 + rr;
                float gm = gamma[c] * rstd;
                float bt = beta[c] - mean * gm;
                const float* xr = x + ((size_t)(b * 64 + c) * 128 + f) * Tt;
                int t0 = lane * 4;
                uint2 pv = {0u, 0u};
                if (t0 + 4 <= Tt) {
                    float4 xv = *(const float4*)&xr[t0];
                    pv.x = (unsigned)f2bf(fmaf(xv.x, gm, bt)) | ((unsigned)f2bf(fmaf(xv.y, gm, bt)) << 16);
                    pv.y = (unsigned)f2bf(fmaf(xv.z, gm, bt)) | ((unsigned)f2bf(fmaf(xv.w, gm, bt)) << 16);
                } else if (t0 < Tt) {                  // t0 == 248
                    float2 xv2 = *(const float2*)&xr[t0];
                    pv.x = (unsigned)f2bf(fmaf(xv2.x, gm, bt)) | ((unsigned)f2bf(fmaf(xv2.y, gm, bt)) << 16);
                }
                *(uint2*)&lt[c * 260 + t0] = pv;       // zeros for t >= 250
            }
            __syncthreads();
            u16* Bb0 = sh + ZT0;                       // 256x72 u16 each, dbuf
            u16* Bb1 = sh + ZT0 + 18432;
            dma72g(W0k, 64, Bb0, 36, w, lane, 16);     // B k=0, overlaps transpose below
            #pragma unroll
            for (int it = 0; it < 2; ++it) {
                int task = it * 1024 + tid;
                int cg = task & 7, t = task >> 3;      // t 0..255
                u16 tmp[8];
                #pragma unroll
                for (int jj = 0; jj < 8; ++jj) tmp[jj] = lt[(cg * 8 + jj) * 260 + t];
                uint4 o;
                o.x = (unsigned)tmp[0] | ((unsigned)tmp[1] << 16);
                o.y = (unsigned)tmp[2] | ((unsigned)tmp[3] << 16);
                o.z = (unsigned)tmp[4] | ((unsigned)tmp[5] << 16);
                o.w = (unsigned)tmp[6] | ((unsigned)tmp[7] << 16);
                *(uint4*)&Hs[t * 72 + cg * 8] = o;
            }
            __syncthreads();                           // drains B k=0 DMA too
            // ---- fused layer-0 GEMM over kernel taps k
            f32x4 acc[16];
            #pragma unroll
            for (int nt = 0; nt < 16; ++nt) acc[nt] = (f32x4){0.f, 0.f, 0.f, 0.f};
            #pragma unroll
            for (int k = 0; k < 8; ++k) {
                u16* Bl = (k & 1) ? Bb1 : Bb0;
                if (k < 7)
                    dma72g(W0k + (size_t)(k + 1) * 16384, 64, (k & 1) ? Bb0 : Bb1, 36, w, lane, 16);
                #pragma unroll
                for (int c2 = 0; c2 < 2; ++c2) {
                    int c0 = c2 * 32;
                    bf16x8 af = *(const bf16x8*)&Hs[(w * 16 + ml + k) * 72 + c0 + q * 8];
                    #pragma unroll
                    for (int nt = 0; nt < 16; ++nt) {
                        bf16x8 bfr = *(const bf16x8*)&Bl[(nt * 16 + ml) * 72 + c0 + q * 8];
                        acc[nt] = __builtin_amdgcn_mfma_f32_16x16x32_bf16(af, bfr, acc[nt], 0, 0, 0);
                    }
                }
                __syncthreads();
            }
            epi16(acc, ZT, FT, Rs, Xs, w, ml, q);
            __syncthreads();
        } else {
            // recurrent GEMM: B tile [256 j][64 c] DMA'd into padded Bst (dead ZT/FT span)
            u16* Bst = sh + ZT0;                       // 256x72
            const u16* Wl = Wrt + (size_t)(lay - 1) * 16384;
            dma72g(Wl, 64, Bst, 36, w, lane, 16);
            __syncthreads();                           // drains DMA; Hs ready from h-phase
            f32x4 acc[16];
            #pragma unroll
            for (int nt = 0; nt < 16; ++nt) acc[nt] = (f32x4){0.f, 0.f, 0.f, 0.f};
            #pragma unroll
            for (int c2 = 0; c2 < 2; ++c2) {
                int c0 = c2 * 32;
                bf16x8 af = *(const bf16x8*)&Hs[(w * 16 + ml + 7) * 72 + c0 + q * 8];
                #pragma unroll
                for (int nt = 0; nt < 16; ++nt) {
                    bf16x8 bfr = *(const bf16x8*)&Bst[(nt * 16 + ml) * 72 + c0 + q * 8];
                    acc[nt] = __builtin_amdgcn_mfma_f32_16x16x32_bf16(af, bfr, acc[nt], 0, 0, 0);
                }
            }
            __syncthreads();   // all B reads done -> ZT/FT writable
            epi16(acc, ZT, FT, Rs, Xs, w, ml, q);
            __syncthreads();
        }

        const float* vv = v + (size_t)(lay * 2) * 64;
        const float* bv = bbias + (size_t)(lay * 2) * 64;

        // serial c-chains: wave0 d0 (forward), wave1 d1 (backward)
        if (w < 2 && lane < 32) {
            const int d = w, h = lane;
            const float vf = vv[d * 64 + h], bf_ = bv[d * 64 + h];
            const float kf = -LOG2E * vf;
            u16* Zr = &ZT[(d * 32 + h) * 248];
            u16* Fr = &FT[(d * 32 + h) * 248];
            if (d == 0) chain_run<0>(Zr, Fr, kf, bf_);
            else        chain_run<1>(Zr, Fr, kf, bf_);
        }
        __syncthreads();

        // h-phase (parallel) + one-time guard zero
        if (lay == 0) {
            for (int i = tid; i < 21 * 72; i += 1024) {
                int r = i / 72, ci = i - r * 72;
                int row = r < 7 ? r : (TnN + r);
                Hs[row * 72 + ci] = 0;
            }
        }
        for (int task = tid; task < 1984; task += 1024) {
            int h = task & 31, d = (task >> 5) & 1, grp = task >> 6;
            int gb = grp * 8;
            const float vr_ = vv[d * 64 + 32 + h], br_ = bv[d * 64 + 32 + h];
            const float kr = -LOG2E * vr_;
            const u16* Cr = &ZT[(d * 32 + h) * 248];
            bf16x8 c8 = *(const bf16x8*)&Cr[gb];
            float cl[8];
            #pragma unroll
            for (int k = 0; k < 8; ++k) cl[k] = (float)c8[k];
            #pragma unroll
            for (int k = 0; k < 8; ++k) {
                int t = gb + k;
                if (t < TnN) {
                    float cpr;
                    if (d == 0) cpr = (t == 0) ? 0.f : (k ? cl[k - 1] : bf2f(Cr[gb - 1]));
                    else        cpr = (t == TnN - 1) ? 0.f : (k < 7 ? cl[k + 1] : bf2f(Cr[gb + 8]));
                    float ur = bf2f(Rs[d * 7776 + t * 32 + h]);
                    float ux = bf2f(Xs[d * 7776 + t * 32 + h]);
                    float xr = fmaf(kr, cpr, -LOG2E * (ur + br_));
                    float rg = __builtin_amdgcn_rcpf(1.f + hw_exp2(xr));
                    float hv = fmaf(rg, cl[k] - ux, ux);
                    Hs[(t + 7) * 72 + d * 32 + h] = f2bf(hv);
                }
            }
        }
        __syncthreads();
    }

    // ---- conv phase: A = Hs, B DMA'd 64-col tiles (2 kc per phase), 8 barriers ----
    {
        u16* Bs0 = sh + ZT0;                      // 64x72 each
        u16* Bs1 = sh + ZT0 + 4608;
        float* Cf = (float*)(sh + ZT0 + 9216);    // 250 x 68 fp32 (dead span after buffers)
        f32x4 acc[4] = {};
        dma72g(Wc, 512, Bs0, 9, w, lane, 16);     // cols 0..63
        __syncthreads();
        #pragma unroll
        for (int m = 0; m < 8; ++m) {             // kernel tap m = kc>>1
            if (m < 7)
                dma72g(Wc + (m + 1) * 64, 512, (m & 1) ? Bs0 : Bs1, 9, w, lane, 16);
            u16* Bl = (m & 1) ? Bs1 : Bs0;
            #pragma unroll
            for (int c2 = 0; c2 < 2; ++c2) {
                int ci0 = c2 * 32;
                bf16x8 af = *(const bf16x8*)&Hs[(w * 16 + ml - m + 7) * 72 + ci0 + q * 8];
                #pragma unroll
                for (int nt = 0; nt < 4; ++nt) {
                    bf16x8 bfv = *(const bf16x8*)&Bl[(nt * 16 + ml) * 72 + ci0 + q * 8];
                    acc[nt] = __builtin_amdgcn_mfma_f32_16x16x32_bf16(af, bfv, acc[nt], 0, 0, 0);
                }
            }
            if (m < 7) __syncthreads();
        }
        float bc[4];
        #pragma unroll
        for (int nt = 0; nt < 4; ++nt) bc[nt] = bct[nt * 16 + ml];
        #pragma unroll
        for (int r = 0; r < 4; ++r) {
            int t = w * 16 + q * 4 + r;
            if (t < Tt) {
                #pragma unroll
                for (int nt = 0; nt < 4; ++nt)
                    Cf[t * 68 + nt * 16 + ml] = acc[nt][r] + bc[nt];
            }
        }
        __syncthreads();
        {
            const int sub = tid & 15;
            const int o = tid >> 4;               // 0..63
            const float* xrow = x + ((size_t)(b * 64 + o) * 128 + f) * Tt;
            float* orow = out + ((size_t)(b * 64 + o) * 128 + f) * Tt;
            #pragma unroll
            for (int it = 0; it < 8; ++it) {
                int j = it * 32 + sub * 2;
                if (j < Tt) {
                    float2 xv = *(const float2*)&xrow[j];
                    float2 ov;
                    ov.x = Cf[j * 68 + o] + xv.x;
                    ov.y = Cf[(j + 1) * 68 + o] + xv.y;
                    *(float2*)&orow[j] = ov;
                }
            }
        }
    }
}

extern "C" void kernel_launch(void* const* d_in, const int* in_sizes, int n_in,
                              void* d_out, int out_size, void* d_ws, size_t ws_size,
                              hipStream_t stream) {
    (void)in_sizes; (void)n_in; (void)out_size; (void)ws_size;
    const float* x     = (const float*)d_in[0];
    const float* gamma = (const float*)d_in[1];
    const float* beta  = (const float*)d_in[2];
    const float* W0    = (const float*)d_in[3];
    const float* Wr    = (const float*)d_in[4];
    const float* v     = (const float*)d_in[5];
    const float* bb    = (const float*)d_in[6];
    const float* wct   = (const float*)d_in[7];
    const float* bct   = (const float*)d_in[8];
    float* out = (float*)d_out;

    char* base = (char*)d_ws;
    float* stats = (float*)base;
    u16* W0k  = (u16*)(base + 256);                      // 262144 B  [8 k][256 j][64 c]
    u16* Wrt  = (u16*)(base + 256 + 262144);             // 98304 B
    u16* Wcto = (u16*)(base + 256 + 262144 + 98304);     // 65536 B

    hipMemsetAsync(stats, 0, 32, stream);
    k_prep<<<dim3(1088), 256, 0, stream>>>(x, W0, Wr, wct, stats, W0k, Wrt, Wcto);
    k_tail<<<dim3(256), 1024, 0, stream>>>(stats, W0k, Wrt, Wcto, v, bb, bct, gamma, beta, x, out);
}

// Round 7
// 188.486 us; speedup vs baseline: 1.2154x; 1.2154x over previous
//
#include <hip/hip_runtime.h>
#include <math.h>

#define Tt 250
#define TnN 243
#define Nn 256
#define EPS_ 1e-5f
#define LOG2E 1.44269504f

typedef unsigned short u16;
typedef __bf16 bf16x8 __attribute__((ext_vector_type(8)));
typedef float f32x4 __attribute__((ext_vector_type(4)));

__device__ __forceinline__ u16 f2bf(float f) {
    unsigned u = __builtin_bit_cast(unsigned, f);
    u += 0x7FFFu + ((u >> 16) & 1u);
    return (u16)(u >> 16);
}
__device__ __forceinline__ float bf2f(u16 s) {
    unsigned u = ((unsigned)s) << 16;
    return __builtin_bit_cast(float, u);
}
__device__ __forceinline__ float hw_exp2(float x) {
    return __builtin_amdgcn_exp2f(x);
}

__device__ __forceinline__ void async_load16(const void* g, void* l) {
    __builtin_amdgcn_global_load_lds(
        (const __attribute__((address_space(1))) unsigned int*)g,
        (__attribute__((address_space(3))) unsigned int*)l, 16, 0, 0);
}

// generalized padded-row DMA: LDS rows of 72 u16 (64 valid + 8 pad), global rows of rstride u16.
// nseg segments of 1024B; seg s covers linear LDS chunks [s*64, s*64+64) x 16B.
__device__ __forceinline__ void dma72g(const u16* gsrc, int rstride, u16* ldst, int nseg,
                                       int w, int lane, int nw) {
    for (int seg = w; seg < nseg; seg += nw) {
        int c9 = seg * 64 + lane;
        int row = c9 / 9, sub = c9 - row * 9;
        const u16* src = (sub < 8) ? &gsrc[row * rstride + sub * 8] : gsrc;
        async_load16(src, ldst + seg * 512);
    }
}

// serial c-chain over one transposed row pair, direction D compile-time.
template<int D>
__device__ __forceinline__ void chain_run(u16* Zr, u16* Fr, float kf, float bf_) {
    bf16x8 z8 = *(const bf16x8*)&Zr[D ? 240 : 0];
    bf16x8 f8 = *(const bf16x8*)&Fr[D ? 240 : 0];
    float c = 0.f;
    for (int grp = 0; grp < 31; ++grp) {
        int gb = D ? (30 - grp) * 8 : grp * 8;
        bf16x8 zn = z8, fn = f8;
        if (grp < 30) {
            int gbn = D ? (29 - grp) * 8 : (grp + 1) * 8;
            zn = *(const bf16x8*)&Zr[gbn];
            fn = *(const bf16x8*)&Fr[gbn];
        }
        bf16x8 co;
        #pragma unroll
        for (int k = 0; k < 8; ++k) {
            const int idx = D ? (7 - k) : k;
            int t = gb + idx;
            float uz = (float)z8[idx];
            float af = -LOG2E * ((float)f8[idx] + bf_);
            float xe = fmaf(kf, c, af);
            float fg = __builtin_amdgcn_rcpf(1.f + hw_exp2(xe));
            float cn = fmaf(fg, c - uz, uz);
            bool ok = (t < TnN);
            if (ok) c = cn;
            co[idx] = ok ? (__bf16)c : (__bf16)0.f;
        }
        *(bf16x8*)&Zr[gb] = co;
        z8 = zn; f8 = fn;
    }
}

// ---------------- combined prep: blocks 0..831 pack weights, 832..1087 stats ----------------
__global__ __launch_bounds__(256) void k_prep(const float* __restrict__ x,
                                              const float* __restrict__ W0,
                                              const float* __restrict__ Wr,
                                              const float* __restrict__ wct,
                                              float* __restrict__ stats,
                                              u16* __restrict__ W0k,
                                              u16* __restrict__ Wrt,
                                              u16* __restrict__ Wcto) {
    __shared__ float ls[4], ls2[4];
    const int bx = blockIdx.x, tid = threadIdx.x;
    if (bx < 832) {
        int idx = bx * 256 + tid;
        if (idx < 131072) {
            int k = idx >> 14, j = (idx >> 6) & 255, c = idx & 63;
            int d = j >> 7, ck = c * 8 + k;
            W0k[idx] = f2bf(W0[((size_t)d * 512 + ck) * 128 + (j & 127)]);
        } else if (idx < 180224) {
            int r = idx - 131072;
            int i = r & 63, j = (r >> 6) & 255, lidx = r >> 14;
            Wrt[r] = f2bf(Wr[(size_t)(lidx * 2 + (j >> 7)) * 8192 + i * 128 + (j & 127)]);
        } else {
            int r = idx - 180224;
            int o = r >> 9; int k = r & 511; int kk = k >> 6, ci = k & 63;
            Wcto[r] = f2bf(wct[(size_t)ci * 512 + o * 8 + kk]);
        }
    } else {
        const int sb = bx - 832;           // 0..255
        const int b = sb >> 7;             // 0,1
        const float4* xb = (const float4*)(x + (size_t)b * 64 * 128 * Tt);
        const int n4 = 64 * 128 * Tt / 4;  // 512000
        float s = 0.f, s2 = 0.f;
        for (int i = (sb & 127) * 256 + tid; i < n4; i += 128 * 256) {
            float4 vv = xb[i];
            s  += vv.x + vv.y + vv.z + vv.w;
            s2 += vv.x * vv.x + vv.y * vv.y + vv.z * vv.z + vv.w * vv.w;
        }
        for (int off = 32; off; off >>= 1) {
            s  += __shfl_down(s, off);
            s2 += __shfl_down(s2, off);
        }
        int lane = tid & 63, w = tid >> 6;
        if (lane == 0) { ls[w] = s; ls2[w] = s2; }
        __syncthreads();
        if (tid == 0) {
            float a = 0.f, a2 = 0.f;
            for (int i = 0; i < 4; i++) { a += ls[i]; a2 += ls2[i]; }
            atomicAdd(&stats[b * 2 + 0], a);
            atomicAdd(&stats[b * 2 + 1], a2);
        }
    }
}

// ---------------- normalize + transpose -> bf16 XbT[n][256 t][64 c] ----------------
__global__ __launch_bounds__(512) void k_norm(const float* __restrict__ x, const float* __restrict__ stats,
                       const float* __restrict__ gamma, const float* __restrict__ beta,
                       u16* __restrict__ xbt) {
    __shared__ u16 lt[64 * 260];
    const int n = blockIdx.x, tid = threadIdx.x;
    const int b = n >> 7, f = n & 127;
    const float inv = 1.0f / (float)(64 * 128 * Tt);
    float mean = stats[b * 2 + 0] * inv;
    float var  = stats[b * 2 + 1] * inv - mean * mean;
    float rstd = rsqrtf(var + EPS_);
    const int c = tid >> 3, vq = tid & 7;
    const float gm = gamma[c] * rstd;
    const float bt = beta[c] - mean * gm;
    const float* xr = x + ((size_t)(b * 64 + c) * 128 + f) * Tt;
    #pragma unroll
    for (int j = 0; j < 16; ++j) {
        int t0 = vq * 2 + j * 16;        // even t, 0..254
        unsigned pv = 0u;
        if (t0 < Tt) {
            float2 xv = *(const float2*)&xr[t0];
            pv = (unsigned)f2bf(fmaf(xv.x, gm, bt)) | ((unsigned)f2bf(fmaf(xv.y, gm, bt)) << 16);
        }
        *(unsigned*)&lt[c * 260 + t0] = pv;   // zeros for t >= 250
    }
    __syncthreads();
    const int cg = tid & 7, tq = tid >> 3;   // tq 0..63
    #pragma unroll
    for (int it = 0; it < 4; ++it) {
        int t = it * 64 + tq;
        u16 tmp[8];
        #pragma unroll
        for (int jj = 0; jj < 8; ++jj) tmp[jj] = lt[(cg * 8 + jj) * 260 + t];
        uint4 o;
        o.x = (unsigned)tmp[0] | ((unsigned)tmp[1] << 16);
        o.y = (unsigned)tmp[2] | ((unsigned)tmp[3] << 16);
        o.z = (unsigned)tmp[4] | ((unsigned)tmp[5] << 16);
        o.w = (unsigned)tmp[6] | ((unsigned)tmp[7] << 16);
        *(uint4*)&xbt[(size_t)n * 16384 + t * 64 + cg * 8] = o;
    }
}

// ---------------- mega tail (1024 threads / 16 waves) ----------------
// LDS map (u16 offsets): Hs 0..19007 (264x72), ZT 19008 (64x248), FT 34880 (64x248),
//                        Bm 50752 (256x72 = 18432, B home / conv taps 0..3; span to 81855).
// lay0 GEMM: Bb0 = ZT0 area (dead), Bb1 = Bm. Conv: taps 4..7 at ZT0, Cf fp32 at u16 37440.
#define HS0 0
#define ZT0 19008
#define FT0 34880
#define BM0 50752
#define SH_U16 81856
__global__ __launch_bounds__(1024) void k_tail(const u16* __restrict__ XbT,
                                               const u16* __restrict__ W0k,
                                               const u16* __restrict__ Wrt,
                                               const u16* __restrict__ Wc,
                                               const float* __restrict__ v,
                                               const float* __restrict__ bbias,
                                               const float* __restrict__ bct,
                                               const float* __restrict__ x,
                                               float* __restrict__ out) {
    __shared__ __align__(16) u16 sh[SH_U16];
    u16* Hs = sh + HS0;
    u16* ZT = sh + ZT0;
    u16* FT = sh + FT0;
    u16* Bm = sh + BM0;
    const int tid = threadIdx.x;
    const int n = blockIdx.x;
    const int lane = tid & 63, w = tid >> 6;          // w in 0..15
    const int ml = lane & 15, q = lane >> 4;
    const int b = n >> 7, f = n & 127;
    const int t0 = w * 16 + q * 4;

    for (int lay = 0; lay < 4; ++lay) {
        f32x4 acc[16];
        #pragma unroll
        for (int nt = 0; nt < 16; ++nt) acc[nt] = (f32x4){0.f, 0.f, 0.f, 0.f};

        if (lay == 0) {
            // fused layer-0 GEMM: acc[t][j] = sum_k sum_c XbT[n][t+k][c] * W0k[k][j][c]
            const u16* Xn = XbT + (size_t)n * 16384;
            u16* Bb0 = sh + ZT0;                       // dead ZT/FT span
            u16* Bb1 = Bm;
            dma72g(Xn, 64, Hs, 36, w, lane, 16);       // A tile rows 0..255
            dma72g(W0k, 64, Bb0, 36, w, lane, 16);     // B k=0
            __syncthreads();
            #pragma unroll
            for (int k = 0; k < 8; ++k) {
                u16* Bl = (k & 1) ? Bb1 : Bb0;
                if (k < 7)
                    dma72g(W0k + (size_t)(k + 1) * 16384, 64, (k & 1) ? Bb0 : Bb1, 36, w, lane, 16);
                #pragma unroll
                for (int c2 = 0; c2 < 2; ++c2) {
                    int c0 = c2 * 32;
                    bf16x8 af = *(const bf16x8*)&Hs[(w * 16 + ml + k) * 72 + c0 + q * 8];
                    #pragma unroll
                    for (int nt = 0; nt < 16; ++nt) {
                        bf16x8 bfr = *(const bf16x8*)&Bl[(nt * 16 + ml) * 72 + c0 + q * 8];
                        acc[nt] = __builtin_amdgcn_mfma_f32_16x16x32_bf16(af, bfr, acc[nt], 0, 0, 0);
                    }
                }
                __syncthreads();
            }
        } else {
            // recurrent GEMM: B pre-staged in Bm (DMA'd under previous layer's chain)
            #pragma unroll
            for (int c2 = 0; c2 < 2; ++c2) {
                int c0 = c2 * 32;
                bf16x8 af = *(const bf16x8*)&Hs[(w * 16 + ml + 7) * 72 + c0 + q * 8];
                #pragma unroll
                for (int nt = 0; nt < 16; ++nt) {
                    bf16x8 bfr = *(const bf16x8*)&Bm[(nt * 16 + ml) * 72 + c0 + q * 8];
                    acc[nt] = __builtin_amdgcn_mfma_f32_16x16x32_bf16(af, bfr, acc[nt], 0, 0, 0);
                }
            }
        }

        // epi8: z/f preacts -> ZT/FT (transposed [h][t]); r/x preacts stay in acc registers.
        // Safe in the MFMA phase: ZT/FT are read/written by nobody else here (lay0: B reads
        // of the aliased Bb0 finished at the k=7-entry barrier).
        if (t0 < TnN) {
            bool vec = (t0 + 4 <= TnN);
            #pragma unroll
            for (int d2 = 0; d2 < 2; ++d2)
                #pragma unroll
                for (int j = 0; j < 4; ++j) {          // j = g2*2+hi, g2 in {0:z,1:f}
                    int nt = d2 * 8 + j;
                    int g2 = j >> 1, hi = j & 1, hh = hi * 16 + ml;
                    u16* P = (g2 ? FT : ZT) + (d2 * 32 + hh) * 248;
                    if (vec) {
                        uint2 pv;
                        pv.x = (unsigned)f2bf(acc[nt][0]) | ((unsigned)f2bf(acc[nt][1]) << 16);
                        pv.y = (unsigned)f2bf(acc[nt][2]) | ((unsigned)f2bf(acc[nt][3]) << 16);
                        *(uint2*)&P[t0] = pv;
                    } else {
                        #pragma unroll
                        for (int r = 0; r < 4; ++r) {
                            int t = t0 + r;
                            if (t < TnN) P[t] = f2bf(acc[nt][r]);
                        }
                    }
                }
        }
        __syncthreads();   // MFMA + epi visible; Bm consumed -> free

        // issue next-B DMA (hidden under the serial chain, drained by chain-end barrier)
        if (lay < 3) {
            dma72g(Wrt + (size_t)lay * 16384, 64, Bm, 36, w, lane, 16);
        } else {
            #pragma unroll
            for (int i = 0; i < 4; ++i)               // conv taps 0..3
                dma72g(Wc + i * 64, 512, Bm + i * 4608, 9, w, lane, 16);
        }

        const float* vv = v + (size_t)(lay * 2) * 64;
        const float* bv = bbias + (size_t)(lay * 2) * 64;

        // serial c-chains: wave0 d0 (forward), wave1 d1 (backward)
        if (w < 2 && lane < 32) {
            const int d = w, h = lane;
            const float vf = vv[d * 64 + h], bf_ = bv[d * 64 + h];
            const float kf = -LOG2E * vf;
            u16* Zr = &ZT[(d * 32 + h) * 248];
            u16* Fr = &FT[(d * 32 + h) * 248];
            if (d == 0) chain_run<0>(Zr, Fr, kf, bf_);
            else        chain_run<1>(Zr, Fr, kf, bf_);
        }
        __syncthreads();   // chain visible; next-B DMA drained

        // h-phase: r/x preacts from registers, c from ZT; writes Hs
        if (lay == 0) {
            for (int i = tid; i < 21 * 72; i += 1024) {
                int r = i / 72, ci = i - r * 72;
                int row = r < 7 ? r : (TnN + r);
                Hs[row * 72 + ci] = 0;
            }
        }
        #pragma unroll
        for (int d2 = 0; d2 < 2; ++d2)
            #pragma unroll
            for (int hi = 0; hi < 2; ++hi) {
                int hh = hi * 16 + ml;
                float vr_ = vv[d2 * 64 + 32 + hh], br_ = bv[d2 * 64 + 32 + hh];
                float kr = -LOG2E * vr_;
                const u16* Cr = &ZT[(d2 * 32 + hh) * 248];
                f32x4 rp = acc[d2 * 8 + 4 + hi];      // r preact (g2=2)
                f32x4 xp = acc[d2 * 8 + 6 + hi];      // x preact (g2=3)
                #pragma unroll
                for (int r = 0; r < 4; ++r) {
                    int t = t0 + r;
                    if (t < TnN) {
                        float ct = bf2f(Cr[t]);
                        float cpr;
                        if (d2 == 0) cpr = (t == 0) ? 0.f : bf2f(Cr[t - 1]);
                        else         cpr = (t == TnN - 1) ? 0.f : bf2f(Cr[t + 1]);
                        float xr = fmaf(kr, cpr, -LOG2E * (rp[r] + br_));
                        float rg = __builtin_amdgcn_rcpf(1.f + hw_exp2(xr));
                        float hv = fmaf(rg, ct - xp[r], xp[r]);
                        Hs[(t + 7) * 72 + d2 * 32 + hh] = f2bf(hv);
                    }
                }
            }
        __syncthreads();
    }

    // ---- conv phase: taps 0..3 pre-staged in Bm; taps 4..7 DMA'd under taps 0..3 ----
    {
        u16* T47 = sh + ZT0;                      // 4 x 4608 (dead ZT/FT)
        float* Cf = (float*)(sh + 37440);         // 250 x 68 fp32 (overlaps Bm tail; barriered)
        f32x4 cacc[4] = {};
        #pragma unroll
        for (int i = 0; i < 4; ++i)
            dma72g(Wc + (4 + i) * 64, 512, T47 + i * 4608, 9, w, lane, 16);
        #pragma unroll
        for (int m = 0; m < 8; ++m) {
            if (m == 4) __syncthreads();          // drain taps 4..7
            const u16* Bl = (m < 4) ? (Bm + m * 4608) : (T47 + (m - 4) * 4608);
            #pragma unroll
            for (int c2 = 0; c2 < 2; ++c2) {
                int ci0 = c2 * 32;
                bf16x8 af = *(const bf16x8*)&Hs[(w * 16 + ml - m + 7) * 72 + ci0 + q * 8];
                #pragma unroll
                for (int nt = 0; nt < 4; ++nt) {
                    bf16x8 bfv = *(const bf16x8*)&Bl[(nt * 16 + ml) * 72 + ci0 + q * 8];
                    cacc[nt] = __builtin_amdgcn_mfma_f32_16x16x32_bf16(af, bfv, cacc[nt], 0, 0, 0);
                }
            }
        }
        __syncthreads();                          // all tap reads done -> Cf region free
        float bc[4];
        #pragma unroll
        for (int nt = 0; nt < 4; ++nt) bc[nt] = bct[nt * 16 + ml];
        #pragma unroll
        for (int r = 0; r < 4; ++r) {
            int t = t0 + r;
            if (t < Tt) {
                #pragma unroll
                for (int nt = 0; nt < 4; ++nt)
                    Cf[t * 68 + nt * 16 + ml] = cacc[nt][r] + bc[nt];
            }
        }
        __syncthreads();
        {
            const int sub = tid & 15;
            const int o = tid >> 4;               // 0..63
            const float* xrow = x + ((size_t)(b * 64 + o) * 128 + f) * Tt;
            float* orow = out + ((size_t)(b * 64 + o) * 128 + f) * Tt;
            #pragma unroll
            for (int it = 0; it < 8; ++it) {
                int j = it * 32 + sub * 2;
                if (j < Tt) {
                    float2 xv = *(const float2*)&xrow[j];
                    float2 ov;
                    ov.x = Cf[j * 68 + o] + xv.x;
                    ov.y = Cf[(j + 1) * 68 + o] + xv.y;
                    *(float2*)&orow[j] = ov;
                }
            }
        }
    }
}

extern "C" void kernel_launch(void* const* d_in, const int* in_sizes, int n_in,
                              void* d_out, int out_size, void* d_ws, size_t ws_size,
                              hipStream_t stream) {
    (void)in_sizes; (void)n_in; (void)out_size; (void)ws_size;
    const float* x     = (const float*)d_in[0];
    const float* gamma = (const float*)d_in[1];
    const float* beta  = (const float*)d_in[2];
    const float* W0    = (const float*)d_in[3];
    const float* Wr    = (const float*)d_in[4];
    const float* v     = (const float*)d_in[5];
    const float* bb    = (const float*)d_in[6];
    const float* wct   = (const float*)d_in[7];
    const float* bct   = (const float*)d_in[8];
    float* out = (float*)d_out;

    char* base = (char*)d_ws;
    float* stats = (float*)base;
    u16* W0k  = (u16*)(base + 256);                      // 262144 B  [8 k][256 j][64 c]
    u16* Wrt  = (u16*)(base + 256 + 262144);             // 98304 B
    u16* Wcto = (u16*)(base + 256 + 262144 + 98304);     // 65536 B
    u16* XbT  = (u16*)(base + 426240);                   // 8.39 MB   [256 n][256 t][64 c]

    hipMemsetAsync(stats, 0, 32, stream);
    k_prep<<<dim3(1088), 256, 0, stream>>>(x, W0, Wr, wct, stats, W0k, Wrt, Wcto);
    k_norm<<<dim3(256), 512, 0, stream>>>(x, stats, gamma, beta, XbT);
    k_tail<<<dim3(256), 1024, 0, stream>>>(XbT, W0k, Wrt, Wcto, v, bb, bct, x, out);
}